// Round 13
// baseline (472.717 us; speedup 1.0000x reference)
//
#include <hip/hip_runtime.h>
#include <hip/hip_bf16.h>

// BS=64 NQ=900 L=1024 D=768 H=256 E=8 TOPK=2 MOE_W=0.5
// out: (64,900,1024) f32
// Sparse MoE via PAIR-bucketing: rows grouped by (top1,top2); one fused kernel
// computes tokens = 0.5*(A@Wp+bp) + c1*(A@We1+be1) + c2*(A@We2+be2) with the
// emb row gathered ONCE. No partial buffer. k3 = 128^2 LDS GEMM, XCD-pinned.

typedef __attribute__((ext_vector_type(8))) short bf16x8;
typedef __attribute__((ext_vector_type(4))) float f32x4;

#define NROW 65536            // 64*1024 token rows
#define CAP2 6144             // per-pair-bucket capacity (stat max ~1300)
#define CSTRIDE 16            // cnt padding: one counter per 64B line
#define SWZ(r) ((((r) & 3) ^ (((r) >> 2) & 3)))

__device__ __forceinline__ unsigned short f2bf(float f) {
    unsigned u = __builtin_bit_cast(unsigned, f);
    u += 0x7fffu + ((u >> 16) & 1u);   // RNE; inputs finite
    return (unsigned short)(u >> 16);
}
__device__ __forceinline__ float bf2f(unsigned short h) {
    unsigned u = ((unsigned)h) << 16;
    return __builtin_bit_cast(float, u);
}
__device__ __forceinline__ void gload16(const void* g, void* l) {
    __builtin_amdgcn_global_load_lds(
        (const __attribute__((address_space(1))) void*)g,
        (__attribute__((address_space(3))) void*)l, 16, 0, 0);
}
__device__ __forceinline__ unsigned cvt_pk_bf16(float a, float b) {
    unsigned r;
    asm("v_cvt_pk_bf16_f32 %0, %1, %2" : "=v"(r) : "v"(a), "v"(b));
    return r;
}

// ---------------------------------------------------------------- kx: x -> bf16
__global__ __launch_bounds__(256) void kx_cast(
    const float* __restrict__ x, unsigned short* __restrict__ x_bf)
{
    int i = blockIdx.x * 256 + threadIdx.x;
    float4 v = ((const float4*)x)[i];
    unsigned long long o = (unsigned long long)cvt_pk_bf16(v.x, v.y) |
                           ((unsigned long long)cvt_pk_bf16(v.z, v.w) << 32);
    __builtin_nontemporal_store(o, (unsigned long long*)x_bf + i);
}

// ---------------------------------------------------------------- k0t: W transpose
__global__ __launch_bounds__(256) void k0_wT(
    const float* __restrict__ proj_w, const float* __restrict__ expert_w,
    unsigned short* __restrict__ wcatT)
{
    int j = blockIdx.z;
    int d0 = blockIdx.x * 64, h0 = blockIdx.y * 64;
    const float* W = (j < 8) ? expert_w + (size_t)j * 768 * 256 : proj_w;
    __shared__ unsigned short s[64][65];
    int t = threadIdx.x;
    #pragma unroll
    for (int i = 0; i < 16; i++) {
        int d = i * 4 + (t >> 6), h = t & 63;
        s[d][h] = f2bf(W[(size_t)(d0 + d) * 256 + h0 + h]);
    }
    __syncthreads();
    #pragma unroll
    for (int i = 0; i < 16; i++) {
        int h = i * 4 + (t >> 6), d = t & 63;
        wcatT[(size_t)(j * 256 + h0 + h) * 768 + d0 + d] = s[d][h];
    }
}

// ---------------------------------------------------------------- kz: bcat, cnt
__global__ __launch_bounds__(256) void kz_misc(
    const float* __restrict__ proj_b, const float* __restrict__ expert_b,
    float* __restrict__ bcat, unsigned* __restrict__ cnt)
{
    int i = blockIdx.x * 256 + threadIdx.x;
    if (i < 2304) {
        int jj = i >> 8, h = i & 255;
        bcat[i] = (jj < 8) ? expert_b[jj * 256 + h] : proj_b[h];
    }
    if (i < 64 * CSTRIDE) cnt[i] = 0;
}

// ---------------------------------------------------------------- K1 (fused, LDS weights):
__global__ __launch_bounds__(256, 4) void k1_fused(
    const float* __restrict__ emb_in, const float* __restrict__ gate_w,
    const float* __restrict__ gate_b, const float* __restrict__ bias_lang,
    const float* __restrict__ bias0, unsigned short* __restrict__ emb_bf,
    unsigned* __restrict__ top2, float2* __restrict__ c2,
    float* __restrict__ tbias)
{
    __shared__ float gwT[9 * 768];     // 27.6 KB
    for (int i = threadIdx.x; i < 768 * 8; i += 256) {
        int d = i >> 3, e = i & 7;
        gwT[e * 768 + d] = gate_w[i];
    }
    for (int i = threadIdx.x; i < 768; i += 256)
        gwT[8 * 768 + i] = bias_lang[i];
    __syncthreads();

    int w = threadIdx.x >> 6, lane = threadIdx.x & 63;
    #pragma unroll 1
    for (int it = 0; it < 8; ++it) {
        int r = blockIdx.x * 32 + w * 8 + it;
        const float4* rv = (const float4*)(emb_in + (size_t)r * 768);
        float4 v0 = rv[lane], v1 = rv[lane + 64], v2 = rv[lane + 128];
        float ss = v0.x*v0.x + v0.y*v0.y + v0.z*v0.z + v0.w*v0.w
                 + v1.x*v1.x + v1.y*v1.y + v1.z*v1.z + v1.w*v1.w
                 + v2.x*v2.x + v2.y*v2.y + v2.z*v2.z + v2.w*v2.w;
        #pragma unroll
        for (int m = 1; m < 64; m <<= 1) ss += __shfl_xor(ss, m, 64);
        float rn = rsqrtf(ss);

        unsigned long long q0 = (unsigned long long)cvt_pk_bf16(v0.x*rn, v0.y*rn) |
                                ((unsigned long long)cvt_pk_bf16(v0.z*rn, v0.w*rn) << 32);
        unsigned long long q1 = (unsigned long long)cvt_pk_bf16(v1.x*rn, v1.y*rn) |
                                ((unsigned long long)cvt_pk_bf16(v1.z*rn, v1.w*rn) << 32);
        unsigned long long q2 = (unsigned long long)cvt_pk_bf16(v2.x*rn, v2.y*rn) |
                                ((unsigned long long)cvt_pk_bf16(v2.z*rn, v2.w*rn) << 32);
        unsigned long long* ob = (unsigned long long*)(emb_bf + (size_t)r * 768);
        __builtin_nontemporal_store(q0, ob + lane);
        __builtin_nontemporal_store(q1, ob + lane + 64);
        __builtin_nontemporal_store(q2, ob + lane + 128);

        float acc[9];
        #pragma unroll
        for (int i = 0; i < 9; i++) acc[i] = 0.f;
        const float4 vv[3] = { v0, v1, v2 };
        #pragma unroll
        for (int k = 0; k < 3; k++) {
            float4 v = vv[k];
            #pragma unroll
            for (int e = 0; e < 9; e++) {
                float4 g = *(const float4*)&gwT[e * 768 + k * 256 + lane * 4];
                acc[e] += v.x*g.x + v.y*g.y + v.z*g.z + v.w*g.w;
            }
        }
        #pragma unroll
        for (int m = 1; m < 64; m <<= 1) {
            #pragma unroll
            for (int i = 0; i < 9; i++) acc[i] += __shfl_xor(acc[i], m, 64);
        }
        if (lane == 0) {
            float g[8];
            #pragma unroll
            for (int e = 0; e < 8; e++) g[e] = acc[e] * rn + gate_b[e];
            float mx = g[0];
            #pragma unroll
            for (int e = 1; e < 8; e++) mx = fmaxf(mx, g[e]);
            float p[8], s = 0.f;
            #pragma unroll
            for (int e = 0; e < 8; e++) { p[e] = __expf(g[e] - mx); s += p[e]; }
            float inv = 0.5f / s;
            int i1 = 0;
            #pragma unroll
            for (int e = 1; e < 8; e++) if (g[e] > g[i1]) i1 = e;
            int i2 = (i1 == 0) ? 1 : 0;
            #pragma unroll
            for (int e = 0; e < 8; e++) if (e != i1 && g[e] > g[i2]) i2 = e;
            top2[r] = (unsigned)i1 | ((unsigned)i2 << 8);
            c2[r]   = make_float2(p[i1] * inv, p[i2] * inv);
            tbias[r] = acc[8] * rn + bias0[0];
        }
    }
}

// ---------------------------------------------------------------- KB (pair-bucket):
// key = top1*8 + top2. LDS-atomic local positions, one global atomic per
// (block,key) on padded counters, guarded scatter of row index + (c1,c2).
__global__ __launch_bounds__(256) void kb_bucket(
    const unsigned* __restrict__ top2, const float2* __restrict__ c2,
    unsigned* __restrict__ cnt, unsigned* __restrict__ bidx,
    float2* __restrict__ bscale2)
{
    __shared__ unsigned lcnt[64];
    __shared__ unsigned gbase[64];
    int tid = threadIdx.x;
    if (tid < 64) lcnt[tid] = 0;
    __syncthreads();
    int r = blockIdx.x * 256 + tid;
    unsigned t = top2[r];
    int key = (int)((t & 255) * 8 + ((t >> 8) & 255));
    unsigned lpos = atomicAdd(&lcnt[key], 1u);
    __syncthreads();
    if (tid < 64)
        gbase[tid] = lcnt[tid] ? atomicAdd(&cnt[tid * CSTRIDE], lcnt[tid]) : 0u;
    __syncthreads();
    unsigned p = gbase[key] + lpos;
    if (p < CAP2) {
        bidx[(size_t)key * CAP2 + p]    = (unsigned)r;
        bscale2[(size_t)key * CAP2 + p] = c2[r];
    }
}

// ---------------------------------------------------------------- K2PAIR:
// Per (key, tile): A-tile (128 gathered rows x 768) LDS-resident per K-half
// (12 slabs of [128][32]); j in {e1, e2, proj} with shared acc, dbuf B;
// fin += c_j * (acc + b_j). One emb gather per row; tokens written once.
__global__ __launch_bounds__(512, 2) void k2_pair(
    const unsigned short* __restrict__ emb_bf, const unsigned short* __restrict__ wcatT,
    const float* __restrict__ bcat, const unsigned* __restrict__ cnt,
    const unsigned* __restrict__ bidx, const float2* __restrict__ bscale2,
    unsigned short* __restrict__ tokens)
{
    int key = blockIdx.y, tile = blockIdx.x;
    int cnt_k = (int)cnt[key * CSTRIDE];
    if (cnt_k > CAP2) cnt_k = CAP2;
    if (tile * 128 >= cnt_k) return;
    int tid = threadIdx.x, lane = tid & 63, w = tid >> 6;
    int wm = w >> 2, wn = w & 3;                 // 2M x 4N waves, 64x64 each
    __shared__ __align__(16) unsigned short As[12 * 4096];    // 96 KB
    __shared__ __align__(16) unsigned short Bs[2][256 * 32];  // 32 KB
    __shared__ unsigned sRow[128];
    __shared__ float2 sC[128];
    if (tid < 128) {
        int gi = tile * 128 + tid;
        if (gi < cnt_k) { sRow[tid] = bidx[(size_t)key * CAP2 + gi];
                          sC[tid]   = bscale2[(size_t)key * CAP2 + gi]; }
        else            { sRow[tid] = 0; sC[tid] = make_float2(0.f, 0.f); }
    }
    __syncthreads();
    int r16 = lane & 15, r4 = lane >> 4;
    int arow = tid >> 2, aseg = (tid & 3) ^ SWZ(arow);
    const unsigned short* aSrc = emb_bf + (size_t)sRow[arow] * 768 + aseg * 8;
    int jmap[3] = { key >> 3, key & 7, 8 };

    auto stageB = [&](int e, int half, int kt, int bbuf) {
        #pragma unroll
        for (int i = 0; i < 2; i++) {
            int u = i * 512 + tid;
            int brow = u >> 2, seg = (u & 3) ^ SWZ(brow);
            gload16(&wcatT[((size_t)e * 256 + brow) * 768 + half * 384 + kt * 32 + seg * 8],
                    &Bs[bbuf][i * 4096 + w * 512]);
        }
    };

    f32x4 fin[4][4];
    #pragma unroll
    for (int mi = 0; mi < 4; mi++)
        #pragma unroll
        for (int ni = 0; ni < 4; ni++) fin[mi][ni] = f32x4{0.f, 0.f, 0.f, 0.f};

    #pragma unroll 1
    for (int half = 0; half < 2; ++half) {
        // stage whole A half: 12 slabs, 12 gloads/thread
        #pragma unroll
        for (int kt = 0; kt < 12; kt++)
            gload16(aSrc + half * 384 + kt * 32, &As[kt * 4096 + w * 512]);
        stageB(jmap[0], half, 0, 0);
        __syncthreads();                          // drains vmcnt: A + B0 ready
        int buf = 0;
        #pragma unroll 1
        for (int j = 0; j < 3; ++j) {
            f32x4 acc[4][4];
            #pragma unroll
            for (int mi = 0; mi < 4; mi++)
                #pragma unroll
                for (int ni = 0; ni < 4; ni++) acc[mi][ni] = f32x4{0.f, 0.f, 0.f, 0.f};
            #pragma unroll 1
            for (int kt = 0; kt < 12; ++kt) {
                int p = j * 12 + kt;
                if (p < 35) { int np = p + 1; stageB(jmap[np / 12], half, np % 12, buf ^ 1); }
                bf16x8 a[4], b[4];
                #pragma unroll
                for (int mi = 0; mi < 4; mi++) {
                    int ar = wm * 64 + mi * 16 + r16;
                    a[mi] = *(const bf16x8*)&As[kt * 4096 + ar * 32 + (r4 ^ SWZ(ar)) * 8];
                }
                #pragma unroll
                for (int ni = 0; ni < 4; ni++) {
                    int br = wn * 64 + ni * 16 + r16;
                    b[ni] = *(const bf16x8*)&Bs[buf][br * 32 + (r4 ^ SWZ(br)) * 8];
                }
                #pragma unroll
                for (int mi = 0; mi < 4; mi++)
                    #pragma unroll
                    for (int ni = 0; ni < 4; ni++)
                        acc[mi][ni] = __builtin_amdgcn_mfma_f32_16x16x32_bf16(
                            a[mi], b[ni], acc[mi][ni], 0, 0, 0);
                __syncthreads();
                buf ^= 1;
            }
            // fold j into fin (bias added once, on half==1)
            float bj[4];
            #pragma unroll
            for (int ni = 0; ni < 4; ni++)
                bj[ni] = half ? bcat[jmap[j] * 256 + wn * 64 + ni * 16 + r16] : 0.f;
            #pragma unroll
            for (int mi = 0; mi < 4; mi++) {
                #pragma unroll
                for (int e4 = 0; e4 < 4; e4++) {
                    int rl = wm * 64 + mi * 16 + r4 * 4 + e4;
                    float c = (j == 0) ? sC[rl].x : (j == 1) ? sC[rl].y : 0.5f;
                    #pragma unroll
                    for (int ni = 0; ni < 4; ni++)
                        fin[mi][ni][e4] += c * (acc[mi][ni][e4] + bj[ni]);
                }
            }
        }
    }

    #pragma unroll
    for (int mi = 0; mi < 4; mi++) {
        #pragma unroll
        for (int e4 = 0; e4 < 4; e4++) {
            int rl = wm * 64 + mi * 16 + r4 * 4 + e4;
            if (tile * 128 + rl < cnt_k) {
                size_t rowg = sRow[rl];
                #pragma unroll
                for (int ni = 0; ni < 4; ni++) {
                    int col = wn * 64 + ni * 16 + r16;
                    __builtin_nontemporal_store(f2bf(fin[mi][ni][e4]),
                                                &tokens[rowg * 256 + col]);
                }
            }
        }
    }
}

// ---------------------------------------------------------------- K3 (128^2 LDS, XCD-pinned):
__global__ __launch_bounds__(256, 4) void k3_logit(
    const unsigned short* __restrict__ x_bf, const unsigned short* __restrict__ tokens,
    const float* __restrict__ tbias, const float* __restrict__ log_scale,
    float* __restrict__ out)
{
    int wgid = blockIdx.x;
    int xcd = wgid & 7, slot = wgid >> 3;
    int b = xcd + 8 * (slot >> 6);
    int t64 = slot & 63;
    int tm = t64 >> 3, tn = t64 & 7;

    int tid = threadIdx.x, lane = tid & 63, w = tid >> 6;
    int wm = w >> 1, wn = w & 1;
    __shared__ __align__(16) unsigned short As[2][128 * 32];
    __shared__ __align__(16) unsigned short Bs[2][128 * 32];
    const unsigned short* A = x_bf + (size_t)b * 900 * 256;
    const unsigned short* B = tokens + (size_t)b * 1024 * 256;
    f32x4 acc[4][4];
    #pragma unroll
    for (int mi = 0; mi < 4; mi++)
        #pragma unroll
        for (int ni = 0; ni < 4; ni++) acc[mi][ni] = f32x4{0.f, 0.f, 0.f, 0.f};
    int r16 = lane & 15, r4 = lane >> 4;

    auto stage = [&](int kt, int buf) {
        #pragma unroll
        for (int i = 0; i < 2; i++) {
            int u = i * 256 + tid;
            int row = u >> 2, seg = (u & 3) ^ SWZ(row);
            int ar = tm * 128 + row;
            if (ar > 899) ar = 899;
            gload16(&A[(size_t)ar * 256 + kt * 32 + seg * 8],
                    &As[buf][i * 2048 + w * 512]);
            int nr = tn * 128 + row;
            gload16(&B[(size_t)nr * 256 + kt * 32 + seg * 8],
                    &Bs[buf][i * 2048 + w * 512]);
        }
    };

    stage(0, 0);
    __syncthreads();
    int buf = 0;
    #pragma unroll 1
    for (int kt = 0; kt < 8; ++kt) {
        if (kt < 7) stage(kt + 1, buf ^ 1);
        bf16x8 a[4], bb[4];
        #pragma unroll
        for (int mi = 0; mi < 4; mi++) {
            int row = wm * 64 + mi * 16 + r16;
            a[mi] = *(const bf16x8*)&As[buf][row * 32 + (r4 ^ SWZ(row)) * 8];
        }
        #pragma unroll
        for (int ni = 0; ni < 4; ni++) {
            int row = wn * 64 + ni * 16 + r16;
            bb[ni] = *(const bf16x8*)&Bs[buf][row * 32 + (r4 ^ SWZ(row)) * 8];
        }
        #pragma unroll
        for (int mi = 0; mi < 4; mi++)
            #pragma unroll
            for (int ni = 0; ni < 4; ni++)
                acc[mi][ni] = __builtin_amdgcn_mfma_f32_16x16x32_bf16(
                    a[mi], bb[ni], acc[mi][ni], 0, 0, 0);
        __syncthreads();
        buf ^= 1;
    }
    float inv = __expf(-log_scale[0]);
    #pragma unroll
    for (int ni = 0; ni < 4; ni++) {
        int l = tn * 128 + wn * 64 + ni * 16 + r16;
        float tbv = tbias[b * 1024 + l];
        #pragma unroll
        for (int mi = 0; mi < 4; mi++) {
            #pragma unroll
            for (int e = 0; e < 4; e++) {
                int q = tm * 128 + wm * 64 + mi * 16 + r4 * 4 + e;
                if (q < 900) {
                    float vv = acc[mi][ni][e] * inv + tbv;
                    vv = fminf(fmaxf(vv, -50000.f), 50000.f);
                    __builtin_nontemporal_store(
                        vv, &out[((size_t)b * 900 + q) * 1024 + l]);
                }
            }
        }
    }
}

// ----------------------------------------------------------------
extern "C" void kernel_launch(void* const* d_in, const int* in_sizes, int n_in,
                              void* d_out, int out_size, void* d_ws, size_t ws_size,
                              hipStream_t stream)
{
    const float* x         = (const float*)d_in[0];
    const float* embedding = (const float*)d_in[1];
    const float* proj_w    = (const float*)d_in[2];
    const float* proj_b    = (const float*)d_in[3];
    const float* gate_w    = (const float*)d_in[4];
    const float* gate_b    = (const float*)d_in[5];
    const float* expert_w  = (const float*)d_in[6];
    const float* expert_b  = (const float*)d_in[7];
    const float* bias_lang = (const float*)d_in[8];
    const float* bias0     = (const float*)d_in[9];
    const float* log_scale = (const float*)d_in[10];
    float* out = (float*)d_out;

    size_t off = 0;
    char* base = (char*)d_ws;
    auto alloc = [&](size_t bytes) -> void* {
        void* p = base + off;
        off += (bytes + 255) & ~(size_t)255;
        return p;
    };
    unsigned short* emb_bf  = (unsigned short*)alloc((size_t)NROW * 768 * 2);     // 100MB
    unsigned short* x_bf    = (unsigned short*)alloc((size_t)14745600 * 2);       // 28MB
    unsigned short* wcatT   = (unsigned short*)alloc((size_t)2304 * 768 * 2);     // 3.4MB
    float* bcat             = (float*)alloc(2304 * 4);
    float* tbias            = (float*)alloc((size_t)NROW * 4);
    unsigned short* tokens  = (unsigned short*)alloc((size_t)NROW * 256 * 2);     // 32MB
    unsigned* cnt           = (unsigned*)alloc(64 * CSTRIDE * 4);
    unsigned* top2          = (unsigned*)alloc((size_t)NROW * 4);                 // 256KB
    float2* c2              = (float2*)alloc((size_t)NROW * 8);                   // 512KB
    unsigned* bidx          = (unsigned*)alloc((size_t)64 * CAP2 * 4);            // 1.6MB
    float2* bscale2         = (float2*)alloc((size_t)64 * CAP2 * 8);              // 3.1MB

    kx_cast<<<14400, 256, 0, stream>>>(x, x_bf);
    dim3 gt(12, 4, 9);
    k0_wT<<<gt, 256, 0, stream>>>(proj_w, expert_w, wcatT);
    kz_misc<<<9, 256, 0, stream>>>(proj_b, expert_b, bcat, cnt);
    k1_fused<<<2048, 256, 0, stream>>>(embedding, gate_w, gate_b, bias_lang, bias0,
                                       emb_bf, top2, c2, tbias);
    kb_bucket<<<NROW / 256, 256, 0, stream>>>(top2, c2, cnt, bidx, bscale2);
    dim3 g2(CAP2 / 128, 64);
    k2_pair<<<g2, 512, 0, stream>>>(emb_bf, wcatT, bcat, cnt, bidx, bscale2, tokens);
    k3_logit<<<4096, 256, 0, stream>>>(x_bf, tokens, tbias, log_scale, out);
}